// Round 5
// baseline (1369.110 us; speedup 1.0000x reference)
//
#include <hip/hip_runtime.h>
#include <hip/hip_cooperative_groups.h>

namespace cg = cooperative_groups;

// 3-layer GraphConv + set pooling + MLP head.
// R19: launch-boundary fusion. Budget audit: per-kernel work sums to ~185us
// vs 280 measured; R15 showed ~4.5us per removed boundary. So: 3 layers +
// pool fused into ONE persistent cooperative kernel (grid.sync between
// stages), blocks stride over tiles. Pool restructured to 32-set tiles
// (same per-set arithmetic order -> identical output) sharing the 256-thread
// block shape. Sentinel rows of xb/b1b/b2b zeroed in p1a2f each launch
// (workspace is re-poisoned). Launches 9 -> 6.

#define FEAT 64
#define SH 9            // coarse bucket = dst >> 9 (512 nodes/bucket)
#define BSZ 512
#define CH 512          // chunk blocks per build job
#define CAP 12288       // max edges per bucket staged in LDS (p2)
#define SCHUNK 1024
#define IDXE 256        // per-wave staged index cap
#define HPAD 8          // LDS row stride = 72 shorts (144B, 16B-aligned)
#define LCHUNK 3200     // p1b2 staging cap (>= ceil(E/CH) = 3125)

typedef unsigned short u16;
typedef __attribute__((ext_vector_type(8))) short bf16x8;
typedef __attribute__((ext_vector_type(4))) float f32x4;

__device__ __forceinline__ float bf2f(u16 u) {
  union { unsigned int i; float f; } c; c.i = ((unsigned int)u) << 16; return c.f;
}
__device__ __forceinline__ u16 f2bf(float f) {
  union { float f; unsigned int i; } c; c.f = f;
  unsigned int u = c.i;
  return (u16)((u + 0x7FFFu + ((u >> 16) & 1u)) >> 16);
}

// ------- pass 1a (fused): per-chunk histograms + cvt + weight prepack -------
__global__ void p1a2f_kernel(const int* __restrict__ kE, int* __restrict__ cE, int nE, int NBe,
                             const int* __restrict__ kP, int* __restrict__ cP, int nP, int NBp,
                             const float* __restrict__ x, u16* __restrict__ xb,
                             u16* __restrict__ s1b, u16* __restrict__ s2b,
                             int n4, int g_cvt,
                             const float* __restrict__ wr0, const float* __restrict__ wl0,
                             const float* __restrict__ wrh, const float* __restrict__ wlh,
                             u16* __restrict__ wpack) {
  __shared__ int hist[256];
  int tid = threadIdx.x, b = blockIdx.x;
  if (b < 2 * CH) {
    const int* keys; int* counts; int nK, NB, c;
    if (b < CH) { keys = kE; counts = cE; nK = nE; NB = NBe; c = b; }
    else        { keys = kP; counts = cP; nK = nP; NB = NBp; c = b - CH; }
    hist[tid] = 0;
    __syncthreads();
    int len = (nK + CH - 1) / CH;
    int cbeg = c * len, cend = min(nK, cbeg + len);
    for (int i = cbeg + tid; i < cend; i += 256) atomicAdd(&hist[keys[i] >> SH], 1);
    __syncthreads();
    if (tid < NB) counts[tid * CH + c] = hist[tid];
  } else if (b < 2 * CH + g_cvt) {
    int i = (b - 2 * CH) * 256 + tid;
    if (i < n4) {
      float4 v = ((const float4*)x)[i];
      ushort4 o = { f2bf(v.x), f2bf(v.y), f2bf(v.z), f2bf(v.w) };
      ((ushort4*)xb)[i] = o;
    }
  } else {
    int t4 = (b - 2 * CH - g_cvt) * 4 + (tid >> 6);   // tile 0..47 (+48 = zero rows)
    if (t4 < 48) {
      int l = t4 >> 4, t = t4 & 15;
      int kt = t >> 2, nt = t & 3;
      int lane = tid & 63;
      const float* wr; const float* wl;
      if (l == 0) { wr = wr0; wl = wl0; }
      else        { wr = wrh + (l - 1) * FEAT * FEAT; wl = wlh + (l - 1) * FEAT * FEAT; }
      int n = nt * 16 + (lane & 15);
      int k0 = kt * 32 + (lane >> 4) * 8;
      u16* dst = wpack + (((size_t)l * 16 + t) * 64 + lane) * 8;
#pragma unroll
      for (int j = 0; j < 8; ++j) {
        int k = k0 + j;
        float v = (k < FEAT) ? wr[k * FEAT + n] : wl[(k - FEAT) * FEAT + n];
        dst[j] = f2bf(v);
      }
    } else if (t4 == 48) {
      // zero sentinel row N of all three feature tables
      int lane = tid & 63;
      if (lane < 48) {
        int Nn = n4 >> 4;
        u16* tb = (lane < 16) ? xb : (lane < 32) ? s1b : s2b;
        int c = lane & 15;
        ushort4 z = {0, 0, 0, 0};
        ((ushort4*)(tb + (size_t)Nn * FEAT))[c] = z;
      }
    }
  }
}

// ---------------- multi-block exclusive scan over counts (both jobs) --------
__global__ void scan1_kernel(int* __restrict__ d0, int* __restrict__ bs0, int L0, int nb0,
                             int* __restrict__ d1, int* __restrict__ bs1, int L1) {
  __shared__ int tsum[256];
  int tid = threadIdx.x, b = blockIdx.x;
  int* data; int* bsums; int L, c;
  if (b < nb0) { data = d0; bsums = bs0; L = L0; c = b; }
  else         { data = d1; bsums = bs1; L = L1; c = b - nb0; }
  int base = c * SCHUNK + tid * 4;
  int v[4];
#pragma unroll
  for (int i = 0; i < 4; ++i) v[i] = (base + i < L) ? data[base + i] : 0;
  int local = v[0] + v[1] + v[2] + v[3];
  tsum[tid] = local;
  __syncthreads();
  for (int off = 1; off < 256; off <<= 1) {
    int u = (tid >= off) ? tsum[tid - off] : 0;
    __syncthreads();
    tsum[tid] += u;
    __syncthreads();
  }
  int excl = tsum[tid] - local;
  if (tid == 255) bsums[c] = tsum[255];
  int run = excl;
#pragma unroll
  for (int i = 0; i < 4; ++i) {
    if (base + i < L) data[base + i] = run;
    run += v[i];
  }
}

// scan3: adds block-sum prefix (computed in-block from raw bsums) and emits
// bucket bases.
__global__ void scan3_kernel(int* __restrict__ d0, const int* __restrict__ bs0,
                             int* __restrict__ bb0, int L0, int NB0, int tot0, int nb0, int g0,
                             int* __restrict__ d1, const int* __restrict__ bs1,
                             int* __restrict__ bb1, int L1, int NB1, int tot1, int nb1) {
  __shared__ int t[256];
  int b = blockIdx.x, tid = threadIdx.x;
  int* data; const int* bsums; int* bbase; int L, NB, tot, nb, i;
  if (b < g0) { data = d0; bsums = bs0; bbase = bb0; L = L0; NB = NB0; tot = tot0; nb = nb0; i = b * 256 + tid; }
  else        { data = d1; bsums = bs1; bbase = bb1; L = L1; NB = NB1; tot = tot1; nb = nb1; i = (b - g0) * 256 + tid; }
  int v = (tid < nb) ? bsums[tid] : 0;
  t[tid] = v;
  __syncthreads();
  for (int off = 1; off < 256; off <<= 1) {
    int u = (tid >= off) ? t[tid - off] : 0;
    __syncthreads();
    t[tid] += u;
    __syncthreads();
  }
  int incl = t[tid];
  __syncthreads();
  t[tid] = incl - v;          // exclusive prefix of block sums
  __syncthreads();
  if (i < L) {
    int val = data[i] + t[i / SCHUNK];
    data[i] = val;
    if ((i & (CH - 1)) == 0) bbase[i / CH] = val;
  }
  if (i == 0) bbase[NB] = tot;
}

// ------- pass 1b: LDS multi-split scatter with coalesced burst writes -------
__global__ void __launch_bounds__(256)
p1b2_kernel(const int* __restrict__ s0, const int* __restrict__ k0,
            const int* __restrict__ c0, int* __restrict__ bin0, int n0, int NB0,
            const int* __restrict__ s1, const int* __restrict__ k1,
            const int* __restrict__ c1, int* __restrict__ bin1, int n1, int NB1) {
  __shared__ int s_bin[LCHUNK];
  __shared__ unsigned char s_bu[LCHUNK];
  __shared__ int lcur[256];
  __shared__ int gdiff[256];
  __shared__ int ts[256];
  int tid = threadIdx.x, b = blockIdx.x;
  const int* src; const int* keys; const int* counts; int* bin; int nE, NB, c;
  if (b < CH) { src = s0; keys = k0; counts = c0; bin = bin0; nE = n0; NB = NB0; c = b; }
  else        { src = s1; keys = k1; counts = c1; bin = bin1; nE = n1; NB = NB1; c = b - CH; }
  int len = (nE + CH - 1) / CH;
  int cbeg = c * len, cend = min(nE, cbeg + len);
  int L = cend - cbeg;

  // derive local bucket counts for this chunk from scanned global offsets
  int cur = 0, v = 0;
  if (tid < NB) {
    int f = tid * CH + c;
    cur = counts[f];
    int nxt = (f + 1 < NB * CH) ? counts[f + 1] : nE;
    v = nxt - cur;
  }
  ts[tid] = v;
  __syncthreads();
  for (int off = 1; off < 256; off <<= 1) {
    int u = (tid >= off) ? ts[tid - off] : 0;
    __syncthreads();
    ts[tid] += u;
    __syncthreads();
  }
  int excl = ts[tid] - v;
  lcur[tid] = excl;
  gdiff[tid] = cur - excl;
  __syncthreads();

  if (L <= LCHUNK) {
    for (int i = cbeg + tid; i < cend; i += 256) {
      int k = keys[i];
      int bu = k >> SH;
      int pos = atomicAdd(&lcur[bu], 1);
      s_bin[pos] = (src[i] << SH) | (k & (BSZ - 1));
      s_bu[pos] = (unsigned char)bu;
    }
    __syncthreads();
    for (int i = tid; i < L; i += 256) {
      int bu = s_bu[i];
      bin[gdiff[bu] + i] = s_bin[i];
    }
  } else {
    for (int i = cbeg + tid; i < cend; i += 256) {
      int k = keys[i];
      int bu = k >> SH;
      int pos = atomicAdd(&lcur[bu], 1);
      bin[gdiff[bu] + pos] = (src[i] << SH) | (k & (BSZ - 1));
    }
  }
}

// ---------------- pass 2: per-bucket fine sort + row_start (both jobs) ------
__global__ void __launch_bounds__(256) p2_kernel(const int* __restrict__ bin0,
                                                 const int* __restrict__ bb0,
                                                 int* __restrict__ csr0, int* __restrict__ rs0,
                                                 int nn0, int NB0,
                                                 const int* __restrict__ bin1,
                                                 const int* __restrict__ bb1,
                                                 int* __restrict__ csr1, int* __restrict__ rs1,
                                                 int nn1) {
  __shared__ int s_csr[CAP];
  __shared__ int hist[BSZ];
  __shared__ int excl[BSZ];
  __shared__ int ts[256];
  int tid = threadIdx.x, bb = blockIdx.x;
  const int* bin; const int* bbase; int* csr; int* rs; int n_nodes, b;
  if (bb < NB0) { bin = bin0; bbase = bb0; csr = csr0; rs = rs0; n_nodes = nn0; b = bb; }
  else          { bin = bin1; bbase = bb1; csr = csr1; rs = rs1; n_nodes = nn1; b = bb - NB0; }
  int base = bbase[b];
  int cnt = bbase[b + 1] - base;
  int node_lo = b * BSZ;
  int nnode = min(BSZ, n_nodes - node_lo);

  hist[tid] = 0; hist[tid + 256] = 0;
  __syncthreads();
  for (int i = tid; i < cnt; i += 256) atomicAdd(&hist[bin[base + i] & (BSZ - 1)], 1);
  __syncthreads();

  int a0 = hist[2 * tid], a1 = hist[2 * tid + 1];
  int pair = a0 + a1;
  ts[tid] = pair;
  __syncthreads();
  for (int off = 1; off < 256; off <<= 1) {
    int u = (tid >= off) ? ts[tid - off] : 0;
    __syncthreads();
    ts[tid] += u;
    __syncthreads();
  }
  int pexcl = ts[tid] - pair;
  excl[2 * tid] = pexcl;
  excl[2 * tid + 1] = pexcl + a0;
  __syncthreads();

  for (int t = tid; t < nnode; t += 256) rs[node_lo + t] = base + excl[t];
  if (tid == 0 && node_lo + nnode >= n_nodes) rs[n_nodes] = bbase[(n_nodes + BSZ - 1) / BSZ];
  hist[tid] = excl[tid]; hist[tid + 256] = excl[tid + 256];
  __syncthreads();

  if (cnt <= CAP) {
    for (int i = tid; i < cnt; i += 256) {
      int e = bin[base + i];
      int pos = atomicAdd(&hist[e & (BSZ - 1)], 1);
      s_csr[pos] = e >> SH;
    }
    __syncthreads();
    for (int i = tid; i < cnt; i += 256) csr[base + i] = s_csr[i];
  } else {
    for (int i = tid; i < cnt; i += 256) {
      int e = bin[base + i];
      int pos = atomicAdd(&hist[e & (BSZ - 1)], 1);
      csr[base + pos] = e >> SH;
    }
  }
}

// ---------------- pipelined gather ----------------
__device__ __forceinline__ float4 reduce_sub(float4 a) {
  a.x += __shfl_xor(a.x, 16, 64); a.y += __shfl_xor(a.y, 16, 64);
  a.z += __shfl_xor(a.z, 16, 64); a.w += __shfl_xor(a.w, 16, 64);
  a.x += __shfl_xor(a.x, 32, 64); a.y += __shfl_xor(a.y, 32, 64);
  a.z += __shfl_xor(a.z, 32, 64); a.w += __shfl_xor(a.w, 32, 64);
  return a;
}

struct RowB { ushort4 a, b, c, e; };

__device__ __forceinline__ RowB load_b16(const u16* __restrict__ hb, const int* idx,
                                         int i, int d, int ch, int sent) {
  int j0 = idx[i], j1 = idx[i + 4], j2 = idx[i + 8], j3 = idx[i + 12];
  j0 = (i      < d) ? j0 : sent;
  j1 = (i + 4  < d) ? j1 : sent;
  j2 = (i + 8  < d) ? j2 : sent;
  j3 = (i + 12 < d) ? j3 : sent;
  RowB r;
  r.a = ((const ushort4*)(hb + (size_t)((unsigned)(j0 * FEAT))))[ch];
  r.b = ((const ushort4*)(hb + (size_t)((unsigned)(j1 * FEAT))))[ch];
  r.c = ((const ushort4*)(hb + (size_t)((unsigned)(j2 * FEAT))))[ch];
  r.e = ((const ushort4*)(hb + (size_t)((unsigned)(j3 * FEAT))))[ch];
  return r;
}

__device__ __forceinline__ float4 acc_b16(float4 acc, RowB r) {
  acc.x += (bf2f(r.a.x) + bf2f(r.b.x)) + (bf2f(r.c.x) + bf2f(r.e.x));
  acc.y += (bf2f(r.a.y) + bf2f(r.b.y)) + (bf2f(r.c.y) + bf2f(r.e.y));
  acc.z += (bf2f(r.a.z) + bf2f(r.b.z)) + (bf2f(r.c.z) + bf2f(r.e.z));
  acc.w += (bf2f(r.a.w) + bf2f(r.b.w)) + (bf2f(r.c.w) + bf2f(r.e.w));
  return acc;
}

// wave-cooperative gather of 8 consecutive rows starting at wbase.
template <class FW>
__device__ __forceinline__ void gather8(const u16* __restrict__ hb,
                                        const int* __restrict__ rs,
                                        const int* __restrict__ csr,
                                        int* sidx, int wbase, int n, int sent,
                                        int sub, int ch, int lane, FW&& wr) {
  int r[9];
#pragma unroll
  for (int j = 0; j < 9; ++j) r[j] = rs[min(wbase + j, n)];
  int rbeg = r[0];
  int run = r[8] - rbeg;
  const int* eb;
  if (run <= IDXE) {
    for (int i = lane; i < run; i += 64) sidx[i] = csr[rbeg + i];
    eb = sidx;
  } else {
    eb = csr + rbeg;
  }
  int nt = min(8, n - wbase);
  if (nt == 8) {
    RowB fn = load_b16(hb, eb, sub, r[1] - r[0], ch, sent);
#pragma unroll
    for (int t = 0; t < 8; ++t) {
      int off = r[t] - rbeg;
      int d = r[t + 1] - r[t];
      RowB cur = fn;
      if (t < 7) fn = load_b16(hb, eb + (r[t + 1] - rbeg), sub, r[t + 2] - r[t + 1], ch, sent);
      float4 acc = {0.f, 0.f, 0.f, 0.f};
      for (int i = sub + 16; i < d; i += 16) {
        RowB nx = load_b16(hb, eb + off, i, d, ch, sent);
        acc = acc_b16(acc, cur);
        cur = nx;
      }
      acc = acc_b16(acc, cur);
      wr(t, reduce_sub(acc));
    }
  } else {
    for (int t = 0; t < nt; ++t) {
      int off = r[t] - rbeg;
      int d = r[t + 1] - r[t];
      float4 acc = {0.f, 0.f, 0.f, 0.f};
      for (int i = sub; i < d; i += 16)
        acc = acc_b16(acc, load_b16(hb, eb + off, i, d, ch, sent));
      wr(t, reduce_sub(acc));
    }
  }
}

// ------- fused main: persistent cooperative, 3 layers + pool + MLP ---------
__global__ void __launch_bounds__(256, 8)
fused_main_kernel(const u16* __restrict__ xb, u16* __restrict__ b1b, u16* __restrict__ b2b,
                  const int* __restrict__ rs_e, const int* __restrict__ csr_e,
                  const u16* __restrict__ wpack,
                  const float* __restrict__ bias0, const float* __restrict__ biash,
                  const int* __restrict__ rs_p, const int* __restrict__ csr_p,
                  const float* __restrict__ fc1_w, const float* __restrict__ fc1_b,
                  const float* __restrict__ fc2_w, const float* __restrict__ fc2_b,
                  const float* __restrict__ fc3_w, const float* __restrict__ fc3_b,
                  float* __restrict__ out, int n, int nsets) {
  __shared__ union {
    struct { u16 h[32][FEAT + HPAD]; u16 a[32][FEAT + HPAD]; int idx[4][IDXE + 16]; } L;
    struct { float p[32][FEAT + 4]; int idx[4][IDXE + 16]; } P;
  } sm;
  cg::grid_group grid = cg::this_grid();
  const int tid = threadIdx.x;
  const int wv = __builtin_amdgcn_readfirstlane(tid >> 6);   // 0..3
  const int lane = tid & 63;
  const int sub = lane >> 4;
  const int ch = lane & 15;

  const int ntl = (n + 31) >> 5;
  for (int l = 0; l < 3; ++l) {
    const u16* hin = (l == 0) ? xb : (l == 1) ? b1b : b2b;
    u16* hout = (l == 0) ? b1b : (l == 1) ? b2b : b1b;
    const u16* wp = wpack + (size_t)l * 16 * 64 * 8;
    const float* bias = (l == 0) ? bias0 : (l == 1) ? biash : biash + FEAT;

    for (int tile = blockIdx.x; tile < ntl; tile += gridDim.x) {
      const int base = tile * 32;
      // phase B: stage own rows raw (coalesced ushort4); 32 rows x 16 quads
      for (int it = 0; it < 2; ++it) {
        int idx = tid + it * 256;
        int nl = idx >> 4, c = idx & 15;
        int node = base + nl;
        if (node < n)
          *(ushort4*)&sm.L.h[nl][c * 4] = ((const ushort4*)(hin + (size_t)node * FEAT))[c];
      }
      // phase A: wave wv gathers nodes [base+wv*8, +8), pipelined
      int wbase = base + wv * 8;
      if (wbase < n) {
        gather8(hin, rs_e, csr_e, &sm.L.idx[wv][0], wbase, n, n, sub, ch, lane,
                [&](int t, float4 acc) {
                  if (sub == 0) {
                    ushort4 o = { f2bf(acc.x), f2bf(acc.y), f2bf(acc.z), f2bf(acc.w) };
                    *(ushort4*)&sm.L.a[wv * 8 + t][ch * 4] = o;
                  }
                });
      }
      __syncthreads();

      // phase C: MFMA over 32x64 out. mt = wv&1, nt pair = (wv>>1)*2, +1.
      const int mt = wv & 1;
      const int ntb = (wv >> 1) * 2;
      const int mrow = mt * 16 + ch;
      const int koff = sub * 8;
      f32x4 acc0 = {0.f, 0.f, 0.f, 0.f};
      f32x4 acc1 = {0.f, 0.f, 0.f, 0.f};
#pragma unroll
      for (int kt = 0; kt < 4; ++kt) {
        bf16x8 a;
        if (kt < 2) a = *(const bf16x8*)&sm.L.h[mrow][kt * 32 + koff];
        else        a = *(const bf16x8*)&sm.L.a[mrow][(kt - 2) * 32 + koff];
        bf16x8 w0 = *(const bf16x8*)&wp[(((size_t)kt * 4 + ntb) * 64 + lane) * 8];
        bf16x8 w1 = *(const bf16x8*)&wp[(((size_t)kt * 4 + ntb + 1) * 64 + lane) * 8];
        acc0 = __builtin_amdgcn_mfma_f32_16x16x32_bf16(a, w0, acc0, 0, 0, 0);
        acc1 = __builtin_amdgcn_mfma_f32_16x16x32_bf16(a, w1, acc1, 0, 0, 0);
      }
      __syncthreads();

      // epilogue: bias + ELU -> bf16 into sm.L.h
      const float bs0 = bias[ntb * 16 + ch];
      const float bs1 = bias[(ntb + 1) * 16 + ch];
      const int rbase = sub * 4;
#pragma unroll
      for (int rg = 0; rg < 4; ++rg) {
        int nl = mt * 16 + rbase + rg;
        float v0 = acc0[rg] + bs0;
        float v1 = acc1[rg] + bs1;
        v0 = v0 > 0.f ? v0 : (__expf(v0) - 1.f);
        v1 = v1 > 0.f ? v1 : (__expf(v1) - 1.f);
        sm.L.h[nl][ntb * 16 + ch] = f2bf(v0);
        sm.L.h[nl][(ntb + 1) * 16 + ch] = f2bf(v1);
      }
      __syncthreads();

      for (int it = 0; it < 2; ++it) {
        int idx = tid + it * 256;
        int nl = idx >> 4, c = idx & 15;
        int node = base + nl;
        if (node < n)
          ((ushort4*)(hout + (size_t)node * FEAT))[c] = *(const ushort4*)&sm.L.h[nl][c * 4];
      }
      __syncthreads();   // LDS reuse guard before next tile
    }
    grid.sync();
  }

  // ---- pool + MLP head: 32-set tiles ----
  const int ntp = (nsets + 31) >> 5;
  const int set = lane & 31;
  const int half = lane >> 5;
  for (int tile = blockIdx.x; tile < ntp; tile += gridDim.x) {
    const int base = tile * 32;
    int wbase = base + wv * 8;
    if (wbase < nsets) {
      gather8(b1b, rs_p, csr_p, &sm.P.idx[wv][0], wbase, nsets, n, sub, ch, lane,
              [&](int t, float4 acc) {
                if (sub == 0) *(float4*)&sm.P.p[wv * 8 + t][ch * 4] = acc;
              });
    }
    __syncthreads();

    // fc1 (64->64) + ELU in place; lane covers (set, 8 cols)
    {
      const int jb = wv * 16 + half * 8;
      float acc[8];
#pragma unroll
      for (int jj = 0; jj < 8; ++jj) acc[jj] = fc1_b[jb + jj];
      for (int k = 0; k < FEAT; k += 4) {
        const float4 pv = *(const float4*)&sm.P.p[set][k];
        const float pk[4] = {pv.x, pv.y, pv.z, pv.w};
#pragma unroll
        for (int kk = 0; kk < 4; ++kk) {
          const float* w = fc1_w + (k + kk) * FEAT + jb;
#pragma unroll
          for (int jj = 0; jj < 8; ++jj) acc[jj] += pk[kk] * w[jj];
        }
      }
      __syncthreads();
#pragma unroll
      for (int jj = 0; jj < 8; ++jj) {
        float a = acc[jj];
        sm.P.p[set][jb + jj] = a > 0.f ? a : (__expf(a) - 1.f);
      }
    }
    __syncthreads();

    // fc2 (64->32) + ELU; lane covers (set, 4 cols)
    {
      const int jb = wv * 8 + half * 4;
      float acc[4];
#pragma unroll
      for (int jj = 0; jj < 4; ++jj) acc[jj] = fc2_b[jb + jj];
      for (int k = 0; k < FEAT; k += 4) {
        const float4 tv = *(const float4*)&sm.P.p[set][k];
        const float tk[4] = {tv.x, tv.y, tv.z, tv.w};
#pragma unroll
        for (int kk = 0; kk < 4; ++kk) {
          const float* w = fc2_w + (k + kk) * 32 + jb;
#pragma unroll
          for (int jj = 0; jj < 4; ++jj) acc[jj] += tk[kk] * w[jj];
        }
      }
      __syncthreads();
#pragma unroll
      for (int jj = 0; jj < 4; ++jj) {
        float a = acc[jj];
        sm.P.p[set][jb + jj] = a > 0.f ? a : (__expf(a) - 1.f);
      }
    }
    __syncthreads();

    // fc3 (32->2) + log_softmax; wave 0 lanes 0..31
    if (wv == 0 && half == 0) {
      int s = base + set;
      if (s < nsets) {
        float a0 = fc3_b[0], a1 = fc3_b[1];
        for (int k = 0; k < 32; k += 4) {
          const float4 tv = *(const float4*)&sm.P.p[set][k];
          const float tk[4] = {tv.x, tv.y, tv.z, tv.w};
#pragma unroll
          for (int kk = 0; kk < 4; ++kk) {
            a0 += tk[kk] * fc3_w[(k + kk) * 2 + 0];
            a1 += tk[kk] * fc3_w[(k + kk) * 2 + 1];
          }
        }
        float m = fmaxf(a0, a1);
        float lse = m + logf(__expf(a0 - m) + __expf(a1 - m));
        float2 r = {a0 - lse, a1 - lse};
        *(float2*)(out + (size_t)s * 2) = r;
      }
    }
    __syncthreads();   // LDS reuse guard before next tile
  }
}

extern "C" void kernel_launch(void* const* d_in, const int* in_sizes, int n_in,
                              void* d_out, int out_size, void* d_ws, size_t ws_size,
                              hipStream_t stream) {
  const float* x        = (const float*)d_in[0];
  const int* edge_src   = (const int*)d_in[1];
  const int* edge_dst   = (const int*)d_in[2];
  const int* gather_idx = (const int*)d_in[3];
  const int* seg_idx    = (const int*)d_in[4];
  const float* w_root0  = (const float*)d_in[5];
  const float* w_rel0   = (const float*)d_in[6];
  const float* b0       = (const float*)d_in[7];
  const float* w_root_h = (const float*)d_in[8];
  const float* w_rel_h  = (const float*)d_in[9];
  const float* b_h      = (const float*)d_in[10];
  const float* fc1_w    = (const float*)d_in[11];
  const float* fc1_b    = (const float*)d_in[12];
  const float* fc2_w    = (const float*)d_in[13];
  const float* fc2_b    = (const float*)d_in[14];
  const float* fc3_w    = (const float*)d_in[15];
  const float* fc3_b    = (const float*)d_in[16];

  const int N = in_sizes[0] / FEAT;
  const int E = in_sizes[1];
  const int A = in_sizes[3];
  const int S = out_size / 2;

  const int NB_e = (N + BSZ - 1) / BSZ;
  const int NB_p = (S + BSZ - 1) / BSZ;
  const int L_e = NB_e * CH, L_p = NB_p * CH;
  const int nb_e = (L_e + SCHUNK - 1) / SCHUNK;
  const int nb_p = (L_p + SCHUNK - 1) / SCHUNK;
  const int g_e = (L_e + 255) / 256, g_p = (L_p + 255) / 256;

  size_t hrow_bytes = (size_t)(N + 1) * FEAT * sizeof(u16);   // +1 sentinel row
  char* ws = (char*)d_ws;
  size_t off = 0;
  auto alloc = [&](size_t bytes) { void* p = ws + off; off += (bytes + 15) & ~(size_t)15; return p; };
  u16* xb       = (u16*)alloc(hrow_bytes);
  u16* b1b      = (u16*)alloc(hrow_bytes);
  u16* b2b      = (u16*)alloc(hrow_bytes);
  int* csr_e    = (int*)alloc((size_t)(E + 16) * 4);          // +16 slack (batch overread)
  int* bin_e    = (int*)alloc((size_t)E * 4);
  int* rs_e     = (int*)alloc((size_t)(N + 1) * 4);
  int* counts_e = (int*)alloc((size_t)L_e * 4);
  int* bbase_e  = (int*)alloc((size_t)(NB_e + 1) * 4);
  int* csr_p    = (int*)alloc((size_t)(A + 16) * 4);
  int* bin_p    = (int*)alloc((size_t)A * 4);
  int* rs_p     = (int*)alloc((size_t)(S + 1) * 4);
  int* counts_p = (int*)alloc((size_t)L_p * 4);
  int* bbase_p  = (int*)alloc((size_t)(NB_p + 1) * 4);
  int* bsums_e  = (int*)alloc(256 * 4);
  int* bsums_p  = (int*)alloc(256 * 4);
  u16* wpack    = (u16*)alloc((size_t)3 * 16 * 64 * 8 * sizeof(u16));

  dim3 blk(256);

  int n4 = N * FEAT / 4;
  int g_cvt = (n4 + 255) / 256;
  int g_pp = 13;   // 12 prepack blocks + 1 sentinel-zero block

  // ---- build both CSRs (+ cvt + prepack folded into pass 1a) ----
  p1a2f_kernel<<<2 * CH + g_cvt + g_pp, blk, 0, stream>>>(
      edge_dst, counts_e, E, NB_e, seg_idx, counts_p, A, NB_p,
      x, xb, b1b, b2b, n4, g_cvt, w_root0, w_rel0, w_root_h, w_rel_h, wpack);
  scan1_kernel<<<nb_e + nb_p, blk, 0, stream>>>(counts_e, bsums_e, L_e, nb_e,
                                                counts_p, bsums_p, L_p);
  scan3_kernel<<<g_e + g_p, blk, 0, stream>>>(counts_e, bsums_e, bbase_e, L_e, NB_e, E, nb_e, g_e,
                                              counts_p, bsums_p, bbase_p, L_p, NB_p, A, nb_p);
  p1b2_kernel<<<2 * CH, blk, 0, stream>>>(edge_src, edge_dst, counts_e, bin_e, E, NB_e,
                                          gather_idx, seg_idx, counts_p, bin_p, A, NB_p);
  p2_kernel<<<NB_e + NB_p, blk, 0, stream>>>(bin_e, bbase_e, csr_e, rs_e, N, NB_e,
                                             bin_p, bbase_p, csr_p, rs_p, S);

  // ---- fused persistent cooperative: 3 layers + pool + MLP ----
  static int coop_grid = 0;
  if (coop_grid == 0) {
    int per = 0;
    hipOccupancyMaxActiveBlocksPerMultiprocessor(&per, fused_main_kernel, 256, 0);
    int cus = 0;
    hipDeviceGetAttribute(&cus, hipDeviceAttributeMultiprocessorCount, 0);
    if (per < 1) per = 1;
    if (cus < 1) cus = 256;
    coop_grid = per * cus;
    int ntl = (N + 31) / 32;
    if (coop_grid > ntl) coop_grid = ntl;
  }
  float* outp = (float*)d_out;
  int nN = N, nS = S;
  void* args[] = {
    (void*)&xb, (void*)&b1b, (void*)&b2b, (void*)&rs_e, (void*)&csr_e, (void*)&wpack,
    (void*)&b0, (void*)&b_h, (void*)&rs_p, (void*)&csr_p,
    (void*)&fc1_w, (void*)&fc1_b, (void*)&fc2_w, (void*)&fc2_b, (void*)&fc3_w, (void*)&fc3_b,
    (void*)&outp, (void*)&nN, (void*)&nS
  };
  hipLaunchCooperativeKernel(fused_main_kernel, dim3(coop_grid), dim3(256),
                             args, 0, stream);
}

// Round 6
// 318.584 us; speedup vs baseline: 4.2975x; 4.2975x over previous
//
#include <hip/hip_runtime.h>

// 3-layer GraphConv + set pooling + MLP head.
// R20: REVERT R19 coop fusion (scratch-spill catastrophe: FETCH 1.2GB/
// WRITE 1.6GB of spill traffic, 33ms cold dispatch). Back to R18 structure
// (280.7us verified). One banked change from R19 (proven correct there):
// pool restructured to 32-set / 256-thread / 4-wave tiles with
// __launch_bounds__(256,8) -- same occupancy treatment that won R18's
// layer gain, now applied to the pool gather (was 512-thr @ ~45% occ).

#define FEAT 64
#define SH 9            // coarse bucket = dst >> 9 (512 nodes/bucket)
#define BSZ 512
#define CH 512          // chunk blocks per build job
#define CAP 12288       // max edges per bucket staged in LDS (p2)
#define SCHUNK 1024
#define IDXE 256        // per-wave staged index cap
#define HPAD 8          // LDS row stride = 72 shorts (144B, 16B-aligned)
#define LCHUNK 3200     // p1b2 staging cap (>= ceil(E/CH) = 3125)

typedef unsigned short u16;
typedef __attribute__((ext_vector_type(8))) short bf16x8;
typedef __attribute__((ext_vector_type(4))) float f32x4;

__device__ __forceinline__ float bf2f(u16 u) {
  union { unsigned int i; float f; } c; c.i = ((unsigned int)u) << 16; return c.f;
}
__device__ __forceinline__ u16 f2bf(float f) {
  union { float f; unsigned int i; } c; c.f = f;
  unsigned int u = c.i;
  return (u16)((u + 0x7FFFu + ((u >> 16) & 1u)) >> 16);
}

// ------- pass 1a (fused): per-chunk histograms + cvt + weight prepack -------
__global__ void p1a2f_kernel(const int* __restrict__ kE, int* __restrict__ cE, int nE, int NBe,
                             const int* __restrict__ kP, int* __restrict__ cP, int nP, int NBp,
                             const float* __restrict__ x, u16* __restrict__ xb, int n4, int g_cvt,
                             const float* __restrict__ wr0, const float* __restrict__ wl0,
                             const float* __restrict__ wrh, const float* __restrict__ wlh,
                             u16* __restrict__ wpack) {
  __shared__ int hist[256];
  int tid = threadIdx.x, b = blockIdx.x;
  if (b < 2 * CH) {
    const int* keys; int* counts; int nK, NB, c;
    if (b < CH) { keys = kE; counts = cE; nK = nE; NB = NBe; c = b; }
    else        { keys = kP; counts = cP; nK = nP; NB = NBp; c = b - CH; }
    hist[tid] = 0;
    __syncthreads();
    int len = (nK + CH - 1) / CH;
    int cbeg = c * len, cend = min(nK, cbeg + len);
    for (int i = cbeg + tid; i < cend; i += 256) atomicAdd(&hist[keys[i] >> SH], 1);
    __syncthreads();
    if (tid < NB) counts[tid * CH + c] = hist[tid];
  } else if (b < 2 * CH + g_cvt) {
    int i = (b - 2 * CH) * 256 + tid;
    if (i < n4) {
      float4 v = ((const float4*)x)[i];
      ushort4 o = { f2bf(v.x), f2bf(v.y), f2bf(v.z), f2bf(v.w) };
      ((ushort4*)xb)[i] = o;
    }
  } else {
    int t4 = (b - 2 * CH - g_cvt) * 4 + (tid >> 6);   // tile 0..47 (+48 = zero row)
    if (t4 < 48) {
      int l = t4 >> 4, t = t4 & 15;
      int kt = t >> 2, nt = t & 3;
      int lane = tid & 63;
      const float* wr; const float* wl;
      if (l == 0) { wr = wr0; wl = wl0; }
      else        { wr = wrh + (l - 1) * FEAT * FEAT; wl = wlh + (l - 1) * FEAT * FEAT; }
      int n = nt * 16 + (lane & 15);
      int k0 = kt * 32 + (lane >> 4) * 8;
      u16* dst = wpack + (((size_t)l * 16 + t) * 64 + lane) * 8;
#pragma unroll
      for (int j = 0; j < 8; ++j) {
        int k = k0 + j;
        float v = (k < FEAT) ? wr[k * FEAT + n] : wl[(k - FEAT) * FEAT + n];
        dst[j] = f2bf(v);
      }
    } else if (t4 == 48) {
      // zero sentinel row N of xb
      int lane = tid & 63;
      if (lane < 16) {
        int Nn = n4 >> 4;
        ushort4 z = {0, 0, 0, 0};
        ((ushort4*)(xb + (size_t)Nn * FEAT))[lane] = z;
      }
    }
  }
}

// ---------------- multi-block exclusive scan over counts (both jobs) --------
__global__ void scan1_kernel(int* __restrict__ d0, int* __restrict__ bs0, int L0, int nb0,
                             int* __restrict__ d1, int* __restrict__ bs1, int L1) {
  __shared__ int tsum[256];
  int tid = threadIdx.x, b = blockIdx.x;
  int* data; int* bsums; int L, c;
  if (b < nb0) { data = d0; bsums = bs0; L = L0; c = b; }
  else         { data = d1; bsums = bs1; L = L1; c = b - nb0; }
  int base = c * SCHUNK + tid * 4;
  int v[4];
#pragma unroll
  for (int i = 0; i < 4; ++i) v[i] = (base + i < L) ? data[base + i] : 0;
  int local = v[0] + v[1] + v[2] + v[3];
  tsum[tid] = local;
  __syncthreads();
  for (int off = 1; off < 256; off <<= 1) {
    int u = (tid >= off) ? tsum[tid - off] : 0;
    __syncthreads();
    tsum[tid] += u;
    __syncthreads();
  }
  int excl = tsum[tid] - local;
  if (tid == 255) bsums[c] = tsum[255];
  int run = excl;
#pragma unroll
  for (int i = 0; i < 4; ++i) {
    if (base + i < L) data[base + i] = run;
    run += v[i];
  }
}

// scan3: adds block-sum prefix (computed in-block from raw bsums) and emits
// bucket bases.
__global__ void scan3_kernel(int* __restrict__ d0, const int* __restrict__ bs0,
                             int* __restrict__ bb0, int L0, int NB0, int tot0, int nb0, int g0,
                             int* __restrict__ d1, const int* __restrict__ bs1,
                             int* __restrict__ bb1, int L1, int NB1, int tot1, int nb1) {
  __shared__ int t[256];
  int b = blockIdx.x, tid = threadIdx.x;
  int* data; const int* bsums; int* bbase; int L, NB, tot, nb, i;
  if (b < g0) { data = d0; bsums = bs0; bbase = bb0; L = L0; NB = NB0; tot = tot0; nb = nb0; i = b * 256 + tid; }
  else        { data = d1; bsums = bs1; bbase = bb1; L = L1; NB = NB1; tot = tot1; nb = nb1; i = (b - g0) * 256 + tid; }
  int v = (tid < nb) ? bsums[tid] : 0;
  t[tid] = v;
  __syncthreads();
  for (int off = 1; off < 256; off <<= 1) {
    int u = (tid >= off) ? t[tid - off] : 0;
    __syncthreads();
    t[tid] += u;
    __syncthreads();
  }
  int incl = t[tid];
  __syncthreads();
  t[tid] = incl - v;          // exclusive prefix of block sums
  __syncthreads();
  if (i < L) {
    int val = data[i] + t[i / SCHUNK];
    data[i] = val;
    if ((i & (CH - 1)) == 0) bbase[i / CH] = val;
  }
  if (i == 0) bbase[NB] = tot;
}

// ------- pass 1b: LDS multi-split scatter with coalesced burst writes -------
__global__ void __launch_bounds__(256)
p1b2_kernel(const int* __restrict__ s0, const int* __restrict__ k0,
            const int* __restrict__ c0, int* __restrict__ bin0, int n0, int NB0,
            const int* __restrict__ s1, const int* __restrict__ k1,
            const int* __restrict__ c1, int* __restrict__ bin1, int n1, int NB1) {
  __shared__ int s_bin[LCHUNK];
  __shared__ unsigned char s_bu[LCHUNK];
  __shared__ int lcur[256];
  __shared__ int gdiff[256];
  __shared__ int ts[256];
  int tid = threadIdx.x, b = blockIdx.x;
  const int* src; const int* keys; const int* counts; int* bin; int nE, NB, c;
  if (b < CH) { src = s0; keys = k0; counts = c0; bin = bin0; nE = n0; NB = NB0; c = b; }
  else        { src = s1; keys = k1; counts = c1; bin = bin1; nE = n1; NB = NB1; c = b - CH; }
  int len = (nE + CH - 1) / CH;
  int cbeg = c * len, cend = min(nE, cbeg + len);
  int L = cend - cbeg;

  // derive local bucket counts for this chunk from scanned global offsets
  int cur = 0, v = 0;
  if (tid < NB) {
    int f = tid * CH + c;
    cur = counts[f];
    int nxt = (f + 1 < NB * CH) ? counts[f + 1] : nE;
    v = nxt - cur;
  }
  ts[tid] = v;
  __syncthreads();
  for (int off = 1; off < 256; off <<= 1) {
    int u = (tid >= off) ? ts[tid - off] : 0;
    __syncthreads();
    ts[tid] += u;
    __syncthreads();
  }
  int excl = ts[tid] - v;
  lcur[tid] = excl;
  gdiff[tid] = cur - excl;
  __syncthreads();

  if (L <= LCHUNK) {
    for (int i = cbeg + tid; i < cend; i += 256) {
      int k = keys[i];
      int bu = k >> SH;
      int pos = atomicAdd(&lcur[bu], 1);
      s_bin[pos] = (src[i] << SH) | (k & (BSZ - 1));
      s_bu[pos] = (unsigned char)bu;
    }
    __syncthreads();
    for (int i = tid; i < L; i += 256) {
      int bu = s_bu[i];
      bin[gdiff[bu] + i] = s_bin[i];
    }
  } else {
    for (int i = cbeg + tid; i < cend; i += 256) {
      int k = keys[i];
      int bu = k >> SH;
      int pos = atomicAdd(&lcur[bu], 1);
      bin[gdiff[bu] + pos] = (src[i] << SH) | (k & (BSZ - 1));
    }
  }
}

// ---------------- pass 2: per-bucket fine sort + row_start (both jobs) ------
__global__ void __launch_bounds__(256) p2_kernel(const int* __restrict__ bin0,
                                                 const int* __restrict__ bb0,
                                                 int* __restrict__ csr0, int* __restrict__ rs0,
                                                 int nn0, int NB0,
                                                 const int* __restrict__ bin1,
                                                 const int* __restrict__ bb1,
                                                 int* __restrict__ csr1, int* __restrict__ rs1,
                                                 int nn1) {
  __shared__ int s_csr[CAP];
  __shared__ int hist[BSZ];
  __shared__ int excl[BSZ];
  __shared__ int ts[256];
  int tid = threadIdx.x, bb = blockIdx.x;
  const int* bin; const int* bbase; int* csr; int* rs; int n_nodes, b;
  if (bb < NB0) { bin = bin0; bbase = bb0; csr = csr0; rs = rs0; n_nodes = nn0; b = bb; }
  else          { bin = bin1; bbase = bb1; csr = csr1; rs = rs1; n_nodes = nn1; b = bb - NB0; }
  int base = bbase[b];
  int cnt = bbase[b + 1] - base;
  int node_lo = b * BSZ;
  int nnode = min(BSZ, n_nodes - node_lo);

  hist[tid] = 0; hist[tid + 256] = 0;
  __syncthreads();
  for (int i = tid; i < cnt; i += 256) atomicAdd(&hist[bin[base + i] & (BSZ - 1)], 1);
  __syncthreads();

  int a0 = hist[2 * tid], a1 = hist[2 * tid + 1];
  int pair = a0 + a1;
  ts[tid] = pair;
  __syncthreads();
  for (int off = 1; off < 256; off <<= 1) {
    int u = (tid >= off) ? ts[tid - off] : 0;
    __syncthreads();
    ts[tid] += u;
    __syncthreads();
  }
  int pexcl = ts[tid] - pair;
  excl[2 * tid] = pexcl;
  excl[2 * tid + 1] = pexcl + a0;
  __syncthreads();

  for (int t = tid; t < nnode; t += 256) rs[node_lo + t] = base + excl[t];
  if (tid == 0 && node_lo + nnode >= n_nodes) rs[n_nodes] = bbase[(n_nodes + BSZ - 1) / BSZ];
  hist[tid] = excl[tid]; hist[tid + 256] = excl[tid + 256];
  __syncthreads();

  if (cnt <= CAP) {
    for (int i = tid; i < cnt; i += 256) {
      int e = bin[base + i];
      int pos = atomicAdd(&hist[e & (BSZ - 1)], 1);
      s_csr[pos] = e >> SH;
    }
    __syncthreads();
    for (int i = tid; i < cnt; i += 256) csr[base + i] = s_csr[i];
  } else {
    for (int i = tid; i < cnt; i += 256) {
      int e = bin[base + i];
      int pos = atomicAdd(&hist[e & (BSZ - 1)], 1);
      csr[base + pos] = e >> SH;
    }
  }
}

// ---------------- pipelined gather ----------------
__device__ __forceinline__ float4 reduce_sub(float4 a) {
  a.x += __shfl_xor(a.x, 16, 64); a.y += __shfl_xor(a.y, 16, 64);
  a.z += __shfl_xor(a.z, 16, 64); a.w += __shfl_xor(a.w, 16, 64);
  a.x += __shfl_xor(a.x, 32, 64); a.y += __shfl_xor(a.y, 32, 64);
  a.z += __shfl_xor(a.z, 32, 64); a.w += __shfl_xor(a.w, 32, 64);
  return a;
}

struct RowB { ushort4 a, b, c, e; };

__device__ __forceinline__ RowB load_b16(const u16* __restrict__ hb, const int* idx,
                                         int i, int d, int ch, int sent) {
  int j0 = idx[i], j1 = idx[i + 4], j2 = idx[i + 8], j3 = idx[i + 12];
  j0 = (i      < d) ? j0 : sent;
  j1 = (i + 4  < d) ? j1 : sent;
  j2 = (i + 8  < d) ? j2 : sent;
  j3 = (i + 12 < d) ? j3 : sent;
  RowB r;
  r.a = ((const ushort4*)(hb + (size_t)((unsigned)(j0 * FEAT))))[ch];
  r.b = ((const ushort4*)(hb + (size_t)((unsigned)(j1 * FEAT))))[ch];
  r.c = ((const ushort4*)(hb + (size_t)((unsigned)(j2 * FEAT))))[ch];
  r.e = ((const ushort4*)(hb + (size_t)((unsigned)(j3 * FEAT))))[ch];
  return r;
}

__device__ __forceinline__ float4 acc_b16(float4 acc, RowB r) {
  acc.x += (bf2f(r.a.x) + bf2f(r.b.x)) + (bf2f(r.c.x) + bf2f(r.e.x));
  acc.y += (bf2f(r.a.y) + bf2f(r.b.y)) + (bf2f(r.c.y) + bf2f(r.e.y));
  acc.z += (bf2f(r.a.z) + bf2f(r.b.z)) + (bf2f(r.c.z) + bf2f(r.e.z));
  acc.w += (bf2f(r.a.w) + bf2f(r.b.w)) + (bf2f(r.c.w) + bf2f(r.e.w));
  return acc;
}

// wave-cooperative gather of 8 consecutive rows starting at wbase.
// Cross-node depth-2 prefetch + pipelined continuation batches within a node.
template <class FW>
__device__ __forceinline__ void gather8(const u16* __restrict__ hb,
                                        const int* __restrict__ rs,
                                        const int* __restrict__ csr,
                                        int* sidx, int wbase, int n, int sent,
                                        int sub, int ch, int lane, FW&& wr) {
  int r[9];
#pragma unroll
  for (int j = 0; j < 9; ++j) r[j] = rs[min(wbase + j, n)];
  int rbeg = r[0];
  int run = r[8] - rbeg;
  const int* eb;
  if (run <= IDXE) {
    for (int i = lane; i < run; i += 64) sidx[i] = csr[rbeg + i];
    eb = sidx;
  } else {
    eb = csr + rbeg;
  }
  int nt = min(8, n - wbase);
  if (nt == 8) {
    RowB fn = load_b16(hb, eb, sub, r[1] - r[0], ch, sent);
#pragma unroll
    for (int t = 0; t < 8; ++t) {
      int off = r[t] - rbeg;
      int d = r[t + 1] - r[t];
      RowB cur = fn;
      if (t < 7) fn = load_b16(hb, eb + (r[t + 1] - rbeg), sub, r[t + 2] - r[t + 1], ch, sent);
      float4 acc = {0.f, 0.f, 0.f, 0.f};
      for (int i = sub + 16; i < d; i += 16) {
        RowB nx = load_b16(hb, eb + off, i, d, ch, sent);
        acc = acc_b16(acc, cur);
        cur = nx;
      }
      acc = acc_b16(acc, cur);
      wr(t, reduce_sub(acc));
    }
  } else {
    for (int t = 0; t < nt; ++t) {
      int off = r[t] - rbeg;
      int d = r[t + 1] - r[t];
      float4 acc = {0.f, 0.f, 0.f, 0.f};
      for (int i = sub; i < d; i += 16)
        acc = acc_b16(acc, load_b16(hb, eb + off, i, d, ch, sent));
      wr(t, reduce_sub(acc));
    }
  }
}

// ---------------- fused layer: 256 threads, 32-node tile ---------
__global__ void __launch_bounds__(256, 8)
layer_fused_kernel(const u16* __restrict__ hb,
                   const int* __restrict__ rs,
                   const int* __restrict__ csr,
                   const u16* __restrict__ wpack,
                   const float* __restrict__ bias,
                   u16* __restrict__ outb, int n) {
  __shared__ u16 s_h[32][FEAT + HPAD];
  __shared__ u16 s_a[32][FEAT + HPAD];
  __shared__ int s_idx[4][IDXE + 16];
  const int tid = threadIdx.x;
  const int wv = __builtin_amdgcn_readfirstlane(tid >> 6);   // 0..3
  const int lane = tid & 63;
  const int sub = lane >> 4;
  const int ch = lane & 15;
  const int base = blockIdx.x * 32;

  // phase B: stage own rows raw (coalesced ushort4); 32 rows x 16 quads
  for (int it = 0; it < 2; ++it) {
    int idx = tid + it * 256;
    int nl = idx >> 4, c = idx & 15;
    int node = base + nl;
    if (node < n)
      *(ushort4*)&s_h[nl][c * 4] = ((const ushort4*)(hb + (size_t)node * FEAT))[c];
  }

  // phase A: wave wv gathers nodes [base+wv*8, +8), pipelined
  int wbase = base + wv * 8;
  if (wbase < n) {
    gather8(hb, rs, csr, &s_idx[wv][0], wbase, n, n, sub, ch, lane,
            [&](int t, float4 acc) {
              if (sub == 0) {
                ushort4 o = { f2bf(acc.x), f2bf(acc.y), f2bf(acc.z), f2bf(acc.w) };
                *(ushort4*)&s_a[wv * 8 + t][ch * 4] = o;
              }
            });
  }
  __syncthreads();

  // phase C: MFMA over 32x64 out. mt = wv&1, nt pair = (wv>>1)*2, +1.
  const int mt = wv & 1;
  const int ntb = (wv >> 1) * 2;
  const int mrow = mt * 16 + (lane & 15);
  const int koff = (lane >> 4) * 8;
  f32x4 acc0 = {0.f, 0.f, 0.f, 0.f};
  f32x4 acc1 = {0.f, 0.f, 0.f, 0.f};
#pragma unroll
  for (int kt = 0; kt < 4; ++kt) {
    bf16x8 a;
    if (kt < 2) a = *(const bf16x8*)&s_h[mrow][kt * 32 + koff];
    else        a = *(const bf16x8*)&s_a[mrow][(kt - 2) * 32 + koff];
    bf16x8 b0 = *(const bf16x8*)&wpack[(((size_t)kt * 4 + ntb) * 64 + lane) * 8];
    bf16x8 b1 = *(const bf16x8*)&wpack[(((size_t)kt * 4 + ntb + 1) * 64 + lane) * 8];
    acc0 = __builtin_amdgcn_mfma_f32_16x16x32_bf16(a, b0, acc0, 0, 0, 0);
    acc1 = __builtin_amdgcn_mfma_f32_16x16x32_bf16(a, b1, acc1, 0, 0, 0);
  }
  __syncthreads();

  // epilogue: bias + ELU -> bf16 into s_h (D: col=lane&15, row=quad*4+reg)
  const int col = lane & 15;
  const int rbase = (lane >> 4) * 4;
  const float bs0 = bias[ntb * 16 + col];
  const float bs1 = bias[(ntb + 1) * 16 + col];
#pragma unroll
  for (int rg = 0; rg < 4; ++rg) {
    int nl = mt * 16 + rbase + rg;
    float v0 = acc0[rg] + bs0;
    float v1 = acc1[rg] + bs1;
    v0 = v0 > 0.f ? v0 : (__expf(v0) - 1.f);
    v1 = v1 > 0.f ? v1 : (__expf(v1) - 1.f);
    s_h[nl][ntb * 16 + col] = f2bf(v0);
    s_h[nl][(ntb + 1) * 16 + col] = f2bf(v1);
  }
  __syncthreads();

  for (int it = 0; it < 2; ++it) {
    int idx = tid + it * 256;
    int nl = idx >> 4, c = idx & 15;
    int node = base + nl;
    if (node < n)
      ((ushort4*)(outb + (size_t)node * FEAT))[c] = *(const ushort4*)&s_h[nl][c * 4];
  }

  // maintain zero sentinel row n of the output table (read by next stage)
  if (blockIdx.x == 0 && tid < 16) {
    ushort4 z = {0, 0, 0, 0};
    ((ushort4*)(outb + (size_t)n * FEAT))[tid] = z;
  }
}

// ------- fused pooling + MLP head: 256 threads, 32-set tile (R19-proven) ----
__global__ void __launch_bounds__(256, 8)
pool_mlp_kernel(const u16* __restrict__ hb,
                const int* __restrict__ rs,
                const int* __restrict__ csr,
                const float* __restrict__ fc1_w, const float* __restrict__ fc1_b,
                const float* __restrict__ fc2_w, const float* __restrict__ fc2_b,
                const float* __restrict__ fc3_w, const float* __restrict__ fc3_b,
                float* __restrict__ out, int nsets, int nnodes) {
  __shared__ float s_p[32][FEAT + 4];
  __shared__ int s_idx[4][IDXE + 16];
  const int tid = threadIdx.x;
  const int wv = __builtin_amdgcn_readfirstlane(tid >> 6);   // 0..3
  const int lane = tid & 63;
  const int sub = lane >> 4;
  const int ch = lane & 15;
  const int base = blockIdx.x * 32;

  int wbase = base + wv * 8;
  if (wbase < nsets) {
    gather8(hb, rs, csr, &s_idx[wv][0], wbase, nsets, nnodes, sub, ch, lane,
            [&](int t, float4 acc) {
              if (sub == 0) *(float4*)&s_p[wv * 8 + t][ch * 4] = acc;
            });
  }
  __syncthreads();

  const int set = lane & 31;
  const int half = lane >> 5;

  // fc1 (64->64) + ELU in place; lane covers (set, 8 cols), jb = wv*16+half*8
  {
    const int jb = wv * 16 + half * 8;
    float acc[8];
#pragma unroll
    for (int jj = 0; jj < 8; ++jj) acc[jj] = fc1_b[jb + jj];
    for (int k = 0; k < FEAT; k += 4) {
      const float4 pv = *(const float4*)&s_p[set][k];
      const float pk[4] = {pv.x, pv.y, pv.z, pv.w};
#pragma unroll
      for (int kk = 0; kk < 4; ++kk) {
        const float* w = fc1_w + (k + kk) * FEAT + jb;
#pragma unroll
        for (int jj = 0; jj < 8; ++jj) acc[jj] += pk[kk] * w[jj];
      }
    }
    __syncthreads();
#pragma unroll
    for (int jj = 0; jj < 8; ++jj) {
      float a = acc[jj];
      s_p[set][jb + jj] = a > 0.f ? a : (__expf(a) - 1.f);
    }
  }
  __syncthreads();

  // fc2 (64->32) + ELU; lane covers (set, 4 cols), jb = wv*8+half*4
  {
    const int jb = wv * 8 + half * 4;
    float acc[4];
#pragma unroll
    for (int jj = 0; jj < 4; ++jj) acc[jj] = fc2_b[jb + jj];
    for (int k = 0; k < FEAT; k += 4) {
      const float4 tv = *(const float4*)&s_p[set][k];
      const float tk[4] = {tv.x, tv.y, tv.z, tv.w};
#pragma unroll
      for (int kk = 0; kk < 4; ++kk) {
        const float* w = fc2_w + (k + kk) * 32 + jb;
#pragma unroll
        for (int jj = 0; jj < 4; ++jj) acc[jj] += tk[kk] * w[jj];
      }
    }
    __syncthreads();
#pragma unroll
    for (int jj = 0; jj < 4; ++jj) {
      float a = acc[jj];
      s_p[set][jb + jj] = a > 0.f ? a : (__expf(a) - 1.f);
    }
  }
  __syncthreads();

  // fc3 (32->2) + log_softmax; wave 0 lanes 0..31
  if (wv == 0 && half == 0) {
    int s = base + set;
    if (s < nsets) {
      float a0 = fc3_b[0], a1 = fc3_b[1];
      for (int k = 0; k < 32; k += 4) {
        const float4 tv = *(const float4*)&s_p[set][k];
        const float tk[4] = {tv.x, tv.y, tv.z, tv.w};
#pragma unroll
        for (int kk = 0; kk < 4; ++kk) {
          a0 += tk[kk] * fc3_w[(k + kk) * 2 + 0];
          a1 += tk[kk] * fc3_w[(k + kk) * 2 + 1];
        }
      }
      float m = fmaxf(a0, a1);
      float lse = m + logf(__expf(a0 - m) + __expf(a1 - m));
      float2 r = {a0 - lse, a1 - lse};
      *(float2*)(out + (size_t)s * 2) = r;
    }
  }
}

extern "C" void kernel_launch(void* const* d_in, const int* in_sizes, int n_in,
                              void* d_out, int out_size, void* d_ws, size_t ws_size,
                              hipStream_t stream) {
  const float* x        = (const float*)d_in[0];
  const int* edge_src   = (const int*)d_in[1];
  const int* edge_dst   = (const int*)d_in[2];
  const int* gather_idx = (const int*)d_in[3];
  const int* seg_idx    = (const int*)d_in[4];
  const float* w_root0  = (const float*)d_in[5];
  const float* w_rel0   = (const float*)d_in[6];
  const float* b0       = (const float*)d_in[7];
  const float* w_root_h = (const float*)d_in[8];
  const float* w_rel_h  = (const float*)d_in[9];
  const float* b_h      = (const float*)d_in[10];
  const float* fc1_w    = (const float*)d_in[11];
  const float* fc1_b    = (const float*)d_in[12];
  const float* fc2_w    = (const float*)d_in[13];
  const float* fc2_b    = (const float*)d_in[14];
  const float* fc3_w    = (const float*)d_in[15];
  const float* fc3_b    = (const float*)d_in[16];

  const int N = in_sizes[0] / FEAT;
  const int E = in_sizes[1];
  const int A = in_sizes[3];
  const int S = out_size / 2;

  const int NB_e = (N + BSZ - 1) / BSZ;
  const int NB_p = (S + BSZ - 1) / BSZ;
  const int L_e = NB_e * CH, L_p = NB_p * CH;
  const int nb_e = (L_e + SCHUNK - 1) / SCHUNK;
  const int nb_p = (L_p + SCHUNK - 1) / SCHUNK;
  const int g_e = (L_e + 255) / 256, g_p = (L_p + 255) / 256;

  size_t hrow_bytes = (size_t)(N + 1) * FEAT * sizeof(u16);   // +1 sentinel row
  char* ws = (char*)d_ws;
  size_t off = 0;
  auto alloc = [&](size_t bytes) { void* p = ws + off; off += (bytes + 15) & ~(size_t)15; return p; };
  u16* xb       = (u16*)alloc(hrow_bytes);
  u16* b1b      = (u16*)alloc(hrow_bytes);
  u16* b2b      = (u16*)alloc(hrow_bytes);
  int* csr_e    = (int*)alloc((size_t)(E + 16) * 4);          // +16 slack (batch overread)
  int* bin_e    = (int*)alloc((size_t)E * 4);
  int* rs_e     = (int*)alloc((size_t)(N + 1) * 4);
  int* counts_e = (int*)alloc((size_t)L_e * 4);
  int* bbase_e  = (int*)alloc((size_t)(NB_e + 1) * 4);
  int* csr_p    = (int*)alloc((size_t)(A + 16) * 4);
  int* bin_p    = (int*)alloc((size_t)A * 4);
  int* rs_p     = (int*)alloc((size_t)(S + 1) * 4);
  int* counts_p = (int*)alloc((size_t)L_p * 4);
  int* bbase_p  = (int*)alloc((size_t)(NB_p + 1) * 4);
  int* bsums_e  = (int*)alloc(256 * 4);
  int* bsums_p  = (int*)alloc(256 * 4);
  u16* wpack    = (u16*)alloc((size_t)3 * 16 * 64 * 8 * sizeof(u16));

  dim3 blk(256);

  int n4 = N * FEAT / 4;
  int g_cvt = (n4 + 255) / 256;
  int g_pp = 13;   // 12 prepack blocks + 1 sentinel-zero block

  // ---- build both CSRs (+ cvt + prepack folded into pass 1a) ----
  p1a2f_kernel<<<2 * CH + g_cvt + g_pp, blk, 0, stream>>>(
      edge_dst, counts_e, E, NB_e, seg_idx, counts_p, A, NB_p,
      x, xb, n4, g_cvt, w_root0, w_rel0, w_root_h, w_rel_h, wpack);
  scan1_kernel<<<nb_e + nb_p, blk, 0, stream>>>(counts_e, bsums_e, L_e, nb_e,
                                                counts_p, bsums_p, L_p);
  scan3_kernel<<<g_e + g_p, blk, 0, stream>>>(counts_e, bsums_e, bbase_e, L_e, NB_e, E, nb_e, g_e,
                                              counts_p, bsums_p, bbase_p, L_p, NB_p, A, nb_p);
  p1b2_kernel<<<2 * CH, blk, 0, stream>>>(edge_src, edge_dst, counts_e, bin_e, E, NB_e,
                                          gather_idx, seg_idx, counts_p, bin_p, A, NB_p);
  p2_kernel<<<NB_e + NB_p, blk, 0, stream>>>(bin_e, bbase_e, csr_e, rs_e, N, NB_e,
                                             bin_p, bbase_p, csr_p, rs_p, S);

  int lgrid = (N + 31) / 32;
  int pgrid = (S + 31) / 32;

  // ---- 3 fused GraphConv layers ----
  layer_fused_kernel<<<lgrid, blk, 0, stream>>>(xb, rs_e, csr_e, wpack,
                                                b0, b1b, N);
  layer_fused_kernel<<<lgrid, blk, 0, stream>>>(b1b, rs_e, csr_e, wpack + 16 * 64 * 8,
                                                b_h, b2b, N);
  layer_fused_kernel<<<lgrid, blk, 0, stream>>>(b2b, rs_e, csr_e, wpack + 2 * 16 * 64 * 8,
                                                b_h + FEAT, b1b, N);

  // ---- fused pooling + MLP head + log_softmax ----
  pool_mlp_kernel<<<pgrid, blk, 0, stream>>>(b1b, rs_p, csr_p,
                                             fc1_w, fc1_b, fc2_w, fc2_b, fc3_w, fc3_b,
                                             (float*)d_out, S, N);
}

// Round 7
// 271.221 us; speedup vs baseline: 5.0480x; 1.1746x over previous
//
#include <hip/hip_runtime.h>

// 3-layer GraphConv + set pooling + MLP head.
// R21: revert R20 pool (regressed; occupancy limited by grid/tail, not
// resources -- back to R18's 512-thr pool). New theory: layer gather is
// LLC request-rate-bound (~1.6M req / 40us = 2 req/cyc/XCD). fp8 halves
// the table (12.8->6.4MB vs 4MB L2/XCD): L2 hit ~31%->~58%, cutting LLC
// requests ~2.4x. R16's fp8 null was structure-masked (serial gather was
// latency-bound); this is fp8 ON the pipelined R18 structure. Layer
// gathers read fp8 tables; all compute/root/pool stay bf16/f32.

#define FEAT 64
#define SH 9            // coarse bucket = dst >> 9 (512 nodes/bucket)
#define BSZ 512
#define CH 512          // chunk blocks per build job
#define CAP 12288       // max edges per bucket staged in LDS (p2)
#define SCHUNK 1024
#define IDXE 256        // per-wave staged index cap
#define HPAD 8          // LDS row stride = 72 shorts (144B, 16B-aligned)
#define LCHUNK 3200     // p1b2 staging cap (>= ceil(E/CH) = 3125)

typedef unsigned short u16;
typedef unsigned char u8;
typedef __attribute__((ext_vector_type(8))) short bf16x8;
typedef __attribute__((ext_vector_type(4))) float f32x4;
typedef __attribute__((ext_vector_type(2))) float f32x2;

__device__ __forceinline__ float bf2f(u16 u) {
  union { unsigned int i; float f; } c; c.i = ((unsigned int)u) << 16; return c.f;
}
__device__ __forceinline__ u16 f2bf(float f) {
  union { float f; unsigned int i; } c; c.f = f;
  unsigned int u = c.i;
  return (u16)((u + 0x7FFFu + ((u >> 16) & 1u)) >> 16);
}

// ---- fp8 e4m3 pack/unpack via hw cvt (OCP e4m3fn on gfx950) ----
__device__ __forceinline__ unsigned pack_fp8x4(float a, float b, float c, float d) {
  int lo = __builtin_amdgcn_cvt_pk_fp8_f32(a, b, 0, 0);
  return (unsigned)__builtin_amdgcn_cvt_pk_fp8_f32(c, d, lo, 1);
}
__device__ __forceinline__ float4 unpack_fp8x4(unsigned v) {
  f32x2 lo = __builtin_amdgcn_cvt_pk_f32_fp8(v, 0);
  f32x2 hi = __builtin_amdgcn_cvt_pk_f32_fp8(v, 1);
  float4 r; r.x = lo.x; r.y = lo.y; r.z = hi.x; r.w = hi.y;
  return r;
}

// ------- pass 1a (fused): per-chunk histograms + cvt + weight prepack -------
__global__ void p1a2f_kernel(const int* __restrict__ kE, int* __restrict__ cE, int nE, int NBe,
                             const int* __restrict__ kP, int* __restrict__ cP, int nP, int NBp,
                             const float* __restrict__ x, u16* __restrict__ xb,
                             u8* __restrict__ xb8, int n4, int g_cvt,
                             const float* __restrict__ wr0, const float* __restrict__ wl0,
                             const float* __restrict__ wrh, const float* __restrict__ wlh,
                             u16* __restrict__ wpack) {
  __shared__ int hist[256];
  int tid = threadIdx.x, b = blockIdx.x;
  if (b < 2 * CH) {
    const int* keys; int* counts; int nK, NB, c;
    if (b < CH) { keys = kE; counts = cE; nK = nE; NB = NBe; c = b; }
    else        { keys = kP; counts = cP; nK = nP; NB = NBp; c = b - CH; }
    hist[tid] = 0;
    __syncthreads();
    int len = (nK + CH - 1) / CH;
    int cbeg = c * len, cend = min(nK, cbeg + len);
    for (int i = cbeg + tid; i < cend; i += 256) atomicAdd(&hist[keys[i] >> SH], 1);
    __syncthreads();
    if (tid < NB) counts[tid * CH + c] = hist[tid];
  } else if (b < 2 * CH + g_cvt) {
    int i = (b - 2 * CH) * 256 + tid;
    if (i < n4) {
      float4 v = ((const float4*)x)[i];
      ushort4 o = { f2bf(v.x), f2bf(v.y), f2bf(v.z), f2bf(v.w) };
      ((ushort4*)xb)[i] = o;
      ((unsigned*)xb8)[i] = pack_fp8x4(v.x, v.y, v.z, v.w);
    }
  } else {
    int t4 = (b - 2 * CH - g_cvt) * 4 + (tid >> 6);   // tile 0..47 (+48 = zero rows)
    if (t4 < 48) {
      int l = t4 >> 4, t = t4 & 15;
      int kt = t >> 2, nt = t & 3;
      int lane = tid & 63;
      const float* wr; const float* wl;
      if (l == 0) { wr = wr0; wl = wl0; }
      else        { wr = wrh + (l - 1) * FEAT * FEAT; wl = wlh + (l - 1) * FEAT * FEAT; }
      int n = nt * 16 + (lane & 15);
      int k0 = kt * 32 + (lane >> 4) * 8;
      u16* dst = wpack + (((size_t)l * 16 + t) * 64 + lane) * 8;
#pragma unroll
      for (int j = 0; j < 8; ++j) {
        int k = k0 + j;
        float v = (k < FEAT) ? wr[k * FEAT + n] : wl[(k - FEAT) * FEAT + n];
        dst[j] = f2bf(v);
      }
    } else if (t4 == 48) {
      // zero sentinel row N of xb (bf16) and xb8 (fp8)
      int lane = tid & 63;
      int Nn = n4 >> 4;
      if (lane < 16) {
        ushort4 z = {0, 0, 0, 0};
        ((ushort4*)(xb + (size_t)Nn * FEAT))[lane] = z;
      } else if (lane < 32) {
        ((unsigned*)(xb8 + (size_t)Nn * FEAT))[lane & 15] = 0u;
      }
    }
  }
}

// ---------------- multi-block exclusive scan over counts (both jobs) --------
__global__ void scan1_kernel(int* __restrict__ d0, int* __restrict__ bs0, int L0, int nb0,
                             int* __restrict__ d1, int* __restrict__ bs1, int L1) {
  __shared__ int tsum[256];
  int tid = threadIdx.x, b = blockIdx.x;
  int* data; int* bsums; int L, c;
  if (b < nb0) { data = d0; bsums = bs0; L = L0; c = b; }
  else         { data = d1; bsums = bs1; L = L1; c = b - nb0; }
  int base = c * SCHUNK + tid * 4;
  int v[4];
#pragma unroll
  for (int i = 0; i < 4; ++i) v[i] = (base + i < L) ? data[base + i] : 0;
  int local = v[0] + v[1] + v[2] + v[3];
  tsum[tid] = local;
  __syncthreads();
  for (int off = 1; off < 256; off <<= 1) {
    int u = (tid >= off) ? tsum[tid - off] : 0;
    __syncthreads();
    tsum[tid] += u;
    __syncthreads();
  }
  int excl = tsum[tid] - local;
  if (tid == 255) bsums[c] = tsum[255];
  int run = excl;
#pragma unroll
  for (int i = 0; i < 4; ++i) {
    if (base + i < L) data[base + i] = run;
    run += v[i];
  }
}

// scan3: adds block-sum prefix (computed in-block from raw bsums) and emits
// bucket bases.
__global__ void scan3_kernel(int* __restrict__ d0, const int* __restrict__ bs0,
                             int* __restrict__ bb0, int L0, int NB0, int tot0, int nb0, int g0,
                             int* __restrict__ d1, const int* __restrict__ bs1,
                             int* __restrict__ bb1, int L1, int NB1, int tot1, int nb1) {
  __shared__ int t[256];
  int b = blockIdx.x, tid = threadIdx.x;
  int* data; const int* bsums; int* bbase; int L, NB, tot, nb, i;
  if (b < g0) { data = d0; bsums = bs0; bbase = bb0; L = L0; NB = NB0; tot = tot0; nb = nb0; i = b * 256 + tid; }
  else        { data = d1; bsums = bs1; bbase = bb1; L = L1; NB = NB1; tot = tot1; nb = nb1; i = (b - g0) * 256 + tid; }
  int v = (tid < nb) ? bsums[tid] : 0;
  t[tid] = v;
  __syncthreads();
  for (int off = 1; off < 256; off <<= 1) {
    int u = (tid >= off) ? t[tid - off] : 0;
    __syncthreads();
    t[tid] += u;
    __syncthreads();
  }
  int incl = t[tid];
  __syncthreads();
  t[tid] = incl - v;          // exclusive prefix of block sums
  __syncthreads();
  if (i < L) {
    int val = data[i] + t[i / SCHUNK];
    data[i] = val;
    if ((i & (CH - 1)) == 0) bbase[i / CH] = val;
  }
  if (i == 0) bbase[NB] = tot;
}

// ------- pass 1b: LDS multi-split scatter with coalesced burst writes -------
__global__ void __launch_bounds__(256)
p1b2_kernel(const int* __restrict__ s0, const int* __restrict__ k0,
            const int* __restrict__ c0, int* __restrict__ bin0, int n0, int NB0,
            const int* __restrict__ s1, const int* __restrict__ k1,
            const int* __restrict__ c1, int* __restrict__ bin1, int n1, int NB1) {
  __shared__ int s_bin[LCHUNK];
  __shared__ unsigned char s_bu[LCHUNK];
  __shared__ int lcur[256];
  __shared__ int gdiff[256];
  __shared__ int ts[256];
  int tid = threadIdx.x, b = blockIdx.x;
  const int* src; const int* keys; const int* counts; int* bin; int nE, NB, c;
  if (b < CH) { src = s0; keys = k0; counts = c0; bin = bin0; nE = n0; NB = NB0; c = b; }
  else        { src = s1; keys = k1; counts = c1; bin = bin1; nE = n1; NB = NB1; c = b - CH; }
  int len = (nE + CH - 1) / CH;
  int cbeg = c * len, cend = min(nE, cbeg + len);
  int L = cend - cbeg;

  // derive local bucket counts for this chunk from scanned global offsets
  int cur = 0, v = 0;
  if (tid < NB) {
    int f = tid * CH + c;
    cur = counts[f];
    int nxt = (f + 1 < NB * CH) ? counts[f + 1] : nE;
    v = nxt - cur;
  }
  ts[tid] = v;
  __syncthreads();
  for (int off = 1; off < 256; off <<= 1) {
    int u = (tid >= off) ? ts[tid - off] : 0;
    __syncthreads();
    ts[tid] += u;
    __syncthreads();
  }
  int excl = ts[tid] - v;
  lcur[tid] = excl;
  gdiff[tid] = cur - excl;
  __syncthreads();

  if (L <= LCHUNK) {
    for (int i = cbeg + tid; i < cend; i += 256) {
      int k = keys[i];
      int bu = k >> SH;
      int pos = atomicAdd(&lcur[bu], 1);
      s_bin[pos] = (src[i] << SH) | (k & (BSZ - 1));
      s_bu[pos] = (unsigned char)bu;
    }
    __syncthreads();
    for (int i = tid; i < L; i += 256) {
      int bu = s_bu[i];
      bin[gdiff[bu] + i] = s_bin[i];
    }
  } else {
    for (int i = cbeg + tid; i < cend; i += 256) {
      int k = keys[i];
      int bu = k >> SH;
      int pos = atomicAdd(&lcur[bu], 1);
      bin[gdiff[bu] + pos] = (src[i] << SH) | (k & (BSZ - 1));
    }
  }
}

// ---------------- pass 2: per-bucket fine sort + row_start (both jobs) ------
__global__ void __launch_bounds__(256) p2_kernel(const int* __restrict__ bin0,
                                                 const int* __restrict__ bb0,
                                                 int* __restrict__ csr0, int* __restrict__ rs0,
                                                 int nn0, int NB0,
                                                 const int* __restrict__ bin1,
                                                 const int* __restrict__ bb1,
                                                 int* __restrict__ csr1, int* __restrict__ rs1,
                                                 int nn1) {
  __shared__ int s_csr[CAP];
  __shared__ int hist[BSZ];
  __shared__ int excl[BSZ];
  __shared__ int ts[256];
  int tid = threadIdx.x, bb = blockIdx.x;
  const int* bin; const int* bbase; int* csr; int* rs; int n_nodes, b;
  if (bb < NB0) { bin = bin0; bbase = bb0; csr = csr0; rs = rs0; n_nodes = nn0; b = bb; }
  else          { bin = bin1; bbase = bb1; csr = csr1; rs = rs1; n_nodes = nn1; b = bb - NB0; }
  int base = bbase[b];
  int cnt = bbase[b + 1] - base;
  int node_lo = b * BSZ;
  int nnode = min(BSZ, n_nodes - node_lo);

  hist[tid] = 0; hist[tid + 256] = 0;
  __syncthreads();
  for (int i = tid; i < cnt; i += 256) atomicAdd(&hist[bin[base + i] & (BSZ - 1)], 1);
  __syncthreads();

  int a0 = hist[2 * tid], a1 = hist[2 * tid + 1];
  int pair = a0 + a1;
  ts[tid] = pair;
  __syncthreads();
  for (int off = 1; off < 256; off <<= 1) {
    int u = (tid >= off) ? ts[tid - off] : 0;
    __syncthreads();
    ts[tid] += u;
    __syncthreads();
  }
  int pexcl = ts[tid] - pair;
  excl[2 * tid] = pexcl;
  excl[2 * tid + 1] = pexcl + a0;
  __syncthreads();

  for (int t = tid; t < nnode; t += 256) rs[node_lo + t] = base + excl[t];
  if (tid == 0 && node_lo + nnode >= n_nodes) rs[n_nodes] = bbase[(n_nodes + BSZ - 1) / BSZ];
  hist[tid] = excl[tid]; hist[tid + 256] = excl[tid + 256];
  __syncthreads();

  if (cnt <= CAP) {
    for (int i = tid; i < cnt; i += 256) {
      int e = bin[base + i];
      int pos = atomicAdd(&hist[e & (BSZ - 1)], 1);
      s_csr[pos] = e >> SH;
    }
    __syncthreads();
    for (int i = tid; i < cnt; i += 256) csr[base + i] = s_csr[i];
  } else {
    for (int i = tid; i < cnt; i += 256) {
      int e = bin[base + i];
      int pos = atomicAdd(&hist[e & (BSZ - 1)], 1);
      csr[base + pos] = e >> SH;
    }
  }
}

// ---------------- pipelined gathers ----------------
__device__ __forceinline__ float4 reduce_sub(float4 a) {
  a.x += __shfl_xor(a.x, 16, 64); a.y += __shfl_xor(a.y, 16, 64);
  a.z += __shfl_xor(a.z, 16, 64); a.w += __shfl_xor(a.w, 16, 64);
  a.x += __shfl_xor(a.x, 32, 64); a.y += __shfl_xor(a.y, 32, 64);
  a.z += __shfl_xor(a.z, 32, 64); a.w += __shfl_xor(a.w, 32, 64);
  return a;
}

// ---- bf16 table (pool) ----
struct RowB { ushort4 a, b, c, e; };

__device__ __forceinline__ RowB load_b16(const u16* __restrict__ hb, const int* idx,
                                         int i, int d, int ch, int sent) {
  int j0 = idx[i], j1 = idx[i + 4], j2 = idx[i + 8], j3 = idx[i + 12];
  j0 = (i      < d) ? j0 : sent;
  j1 = (i + 4  < d) ? j1 : sent;
  j2 = (i + 8  < d) ? j2 : sent;
  j3 = (i + 12 < d) ? j3 : sent;
  RowB r;
  r.a = ((const ushort4*)(hb + (size_t)((unsigned)(j0 * FEAT))))[ch];
  r.b = ((const ushort4*)(hb + (size_t)((unsigned)(j1 * FEAT))))[ch];
  r.c = ((const ushort4*)(hb + (size_t)((unsigned)(j2 * FEAT))))[ch];
  r.e = ((const ushort4*)(hb + (size_t)((unsigned)(j3 * FEAT))))[ch];
  return r;
}

__device__ __forceinline__ float4 acc_b16(float4 acc, RowB r) {
  acc.x += (bf2f(r.a.x) + bf2f(r.b.x)) + (bf2f(r.c.x) + bf2f(r.e.x));
  acc.y += (bf2f(r.a.y) + bf2f(r.b.y)) + (bf2f(r.c.y) + bf2f(r.e.y));
  acc.z += (bf2f(r.a.z) + bf2f(r.b.z)) + (bf2f(r.c.z) + bf2f(r.e.z));
  acc.w += (bf2f(r.a.w) + bf2f(r.b.w)) + (bf2f(r.c.w) + bf2f(r.e.w));
  return acc;
}

template <class FW>
__device__ __forceinline__ void gather8(const u16* __restrict__ hb,
                                        const int* __restrict__ rs,
                                        const int* __restrict__ csr,
                                        int* sidx, int wbase, int n, int sent,
                                        int sub, int ch, int lane, FW&& wr) {
  int r[9];
#pragma unroll
  for (int j = 0; j < 9; ++j) r[j] = rs[min(wbase + j, n)];
  int rbeg = r[0];
  int run = r[8] - rbeg;
  const int* eb;
  if (run <= IDXE) {
    for (int i = lane; i < run; i += 64) sidx[i] = csr[rbeg + i];
    eb = sidx;
  } else {
    eb = csr + rbeg;
  }
  int nt = min(8, n - wbase);
  if (nt == 8) {
    RowB fn = load_b16(hb, eb, sub, r[1] - r[0], ch, sent);
#pragma unroll
    for (int t = 0; t < 8; ++t) {
      int off = r[t] - rbeg;
      int d = r[t + 1] - r[t];
      RowB cur = fn;
      if (t < 7) fn = load_b16(hb, eb + (r[t + 1] - rbeg), sub, r[t + 2] - r[t + 1], ch, sent);
      float4 acc = {0.f, 0.f, 0.f, 0.f};
      for (int i = sub + 16; i < d; i += 16) {
        RowB nx = load_b16(hb, eb + off, i, d, ch, sent);
        acc = acc_b16(acc, cur);
        cur = nx;
      }
      acc = acc_b16(acc, cur);
      wr(t, reduce_sub(acc));
    }
  } else {
    for (int t = 0; t < nt; ++t) {
      int off = r[t] - rbeg;
      int d = r[t + 1] - r[t];
      float4 acc = {0.f, 0.f, 0.f, 0.f};
      for (int i = sub; i < d; i += 16)
        acc = acc_b16(acc, load_b16(hb, eb + off, i, d, ch, sent));
      wr(t, reduce_sub(acc));
    }
  }
}

// ---- fp8 table (layer gathers): 64B rows, 16 lanes x dword ----
struct Row8 { unsigned a, b, c, e; };

__device__ __forceinline__ Row8 load_b8(const u8* __restrict__ h8, const int* idx,
                                        int i, int d, int ch, int sent) {
  int j0 = idx[i], j1 = idx[i + 4], j2 = idx[i + 8], j3 = idx[i + 12];
  j0 = (i      < d) ? j0 : sent;
  j1 = (i + 4  < d) ? j1 : sent;
  j2 = (i + 8  < d) ? j2 : sent;
  j3 = (i + 12 < d) ? j3 : sent;
  Row8 r;
  r.a = ((const unsigned*)(h8 + (size_t)((unsigned)(j0 * FEAT))))[ch];
  r.b = ((const unsigned*)(h8 + (size_t)((unsigned)(j1 * FEAT))))[ch];
  r.c = ((const unsigned*)(h8 + (size_t)((unsigned)(j2 * FEAT))))[ch];
  r.e = ((const unsigned*)(h8 + (size_t)((unsigned)(j3 * FEAT))))[ch];
  return r;
}

__device__ __forceinline__ float4 acc_b8(float4 acc, Row8 r) {
  float4 A = unpack_fp8x4(r.a), B = unpack_fp8x4(r.b);
  float4 C = unpack_fp8x4(r.c), E = unpack_fp8x4(r.e);
  acc.x += (A.x + B.x) + (C.x + E.x);
  acc.y += (A.y + B.y) + (C.y + E.y);
  acc.z += (A.z + B.z) + (C.z + E.z);
  acc.w += (A.w + B.w) + (C.w + E.w);
  return acc;
}

template <class FW>
__device__ __forceinline__ void gather8q(const u8* __restrict__ h8,
                                         const int* __restrict__ rs,
                                         const int* __restrict__ csr,
                                         int* sidx, int wbase, int n, int sent,
                                         int sub, int ch, int lane, FW&& wr) {
  int r[9];
#pragma unroll
  for (int j = 0; j < 9; ++j) r[j] = rs[min(wbase + j, n)];
  int rbeg = r[0];
  int run = r[8] - rbeg;
  const int* eb;
  if (run <= IDXE) {
    for (int i = lane; i < run; i += 64) sidx[i] = csr[rbeg + i];
    eb = sidx;
  } else {
    eb = csr + rbeg;
  }
  int nt = min(8, n - wbase);
  if (nt == 8) {
    Row8 fn = load_b8(h8, eb, sub, r[1] - r[0], ch, sent);
#pragma unroll
    for (int t = 0; t < 8; ++t) {
      int off = r[t] - rbeg;
      int d = r[t + 1] - r[t];
      Row8 cur = fn;
      if (t < 7) fn = load_b8(h8, eb + (r[t + 1] - rbeg), sub, r[t + 2] - r[t + 1], ch, sent);
      float4 acc = {0.f, 0.f, 0.f, 0.f};
      for (int i = sub + 16; i < d; i += 16) {
        Row8 nx = load_b8(h8, eb + off, i, d, ch, sent);
        acc = acc_b8(acc, cur);
        cur = nx;
      }
      acc = acc_b8(acc, cur);
      wr(t, reduce_sub(acc));
    }
  } else {
    for (int t = 0; t < nt; ++t) {
      int off = r[t] - rbeg;
      int d = r[t + 1] - r[t];
      float4 acc = {0.f, 0.f, 0.f, 0.f};
      for (int i = sub; i < d; i += 16)
        acc = acc_b8(acc, load_b8(h8, eb + off, i, d, ch, sent));
      wr(t, reduce_sub(acc));
    }
  }
}

// ---------------- fused layer: 256 threads, 32-node tile, fp8 gather --------
__global__ void __launch_bounds__(256, 8)
layer_fused_kernel(const u16* __restrict__ hb,
                   const u8* __restrict__ g8,
                   const int* __restrict__ rs,
                   const int* __restrict__ csr,
                   const u16* __restrict__ wpack,
                   const float* __restrict__ bias,
                   u16* __restrict__ outb,
                   u8* __restrict__ out8, int n) {
  __shared__ u16 s_h[32][FEAT + HPAD];
  __shared__ u16 s_a[32][FEAT + HPAD];
  __shared__ int s_idx[4][IDXE + 16];
  const int tid = threadIdx.x;
  const int wv = __builtin_amdgcn_readfirstlane(tid >> 6);   // 0..3
  const int lane = tid & 63;
  const int sub = lane >> 4;
  const int ch = lane & 15;
  const int base = blockIdx.x * 32;

  // phase B: stage own rows raw (coalesced ushort4); 32 rows x 16 quads
  for (int it = 0; it < 2; ++it) {
    int idx = tid + it * 256;
    int nl = idx >> 4, c = idx & 15;
    int node = base + nl;
    if (node < n)
      *(ushort4*)&s_h[nl][c * 4] = ((const ushort4*)(hb + (size_t)node * FEAT))[c];
  }

  // phase A: wave wv gathers nodes [base+wv*8, +8) from fp8 table, pipelined
  int wbase = base + wv * 8;
  if (wbase < n) {
    gather8q(g8, rs, csr, &s_idx[wv][0], wbase, n, n, sub, ch, lane,
             [&](int t, float4 acc) {
               if (sub == 0) {
                 ushort4 o = { f2bf(acc.x), f2bf(acc.y), f2bf(acc.z), f2bf(acc.w) };
                 *(ushort4*)&s_a[wv * 8 + t][ch * 4] = o;
               }
             });
  }
  __syncthreads();

  // phase C: MFMA over 32x64 out. mt = wv&1, nt pair = (wv>>1)*2, +1.
  const int mt = wv & 1;
  const int ntb = (wv >> 1) * 2;
  const int mrow = mt * 16 + (lane & 15);
  const int koff = (lane >> 4) * 8;
  f32x4 acc0 = {0.f, 0.f, 0.f, 0.f};
  f32x4 acc1 = {0.f, 0.f, 0.f, 0.f};
#pragma unroll
  for (int kt = 0; kt < 4; ++kt) {
    bf16x8 a;
    if (kt < 2) a = *(const bf16x8*)&s_h[mrow][kt * 32 + koff];
    else        a = *(const bf16x8*)&s_a[mrow][(kt - 2) * 32 + koff];
    bf16x8 b0 = *(const bf16x8*)&wpack[(((size_t)kt * 4 + ntb) * 64 + lane) * 8];
    bf16x8 b1 = *(const bf16x8*)&wpack[(((size_t)kt * 4 + ntb + 1) * 64 + lane) * 8];
    acc0 = __builtin_amdgcn_mfma_f32_16x16x32_bf16(a, b0, acc0, 0, 0, 0);
    acc1 = __builtin_amdgcn_mfma_f32_16x16x32_bf16(a, b1, acc1, 0, 0, 0);
  }
  __syncthreads();

  // epilogue: bias + ELU -> bf16 into s_h (D: col=lane&15, row=quad*4+reg)
  const int col = lane & 15;
  const int rbase = (lane >> 4) * 4;
  const float bs0 = bias[ntb * 16 + col];
  const float bs1 = bias[(ntb + 1) * 16 + col];
#pragma unroll
  for (int rg = 0; rg < 4; ++rg) {
    int nl = mt * 16 + rbase + rg;
    float v0 = acc0[rg] + bs0;
    float v1 = acc1[rg] + bs1;
    v0 = v0 > 0.f ? v0 : (__expf(v0) - 1.f);
    v1 = v1 > 0.f ? v1 : (__expf(v1) - 1.f);
    s_h[nl][ntb * 16 + col] = f2bf(v0);
    s_h[nl][(ntb + 1) * 16 + col] = f2bf(v1);
  }
  __syncthreads();

  for (int it = 0; it < 2; ++it) {
    int idx = tid + it * 256;
    int nl = idx >> 4, c = idx & 15;
    int node = base + nl;
    if (node < n) {
      ushort4 v = *(const ushort4*)&s_h[nl][c * 4];
      ((ushort4*)(outb + (size_t)node * FEAT))[c] = v;
      if (out8)
        ((unsigned*)(out8 + (size_t)node * FEAT))[c] =
            pack_fp8x4(bf2f(v.x), bf2f(v.y), bf2f(v.z), bf2f(v.w));
    }
  }

  // maintain zero sentinel row n of the output tables (read by next stage)
  if (blockIdx.x == 0 && tid < 16) {
    ushort4 z = {0, 0, 0, 0};
    ((ushort4*)(outb + (size_t)n * FEAT))[tid] = z;
    if (out8) ((unsigned*)(out8 + (size_t)n * FEAT))[tid] = 0u;
  }
}

// ---------------- fused pooling + MLP head (R18 512-thread, bf16) -----------
__global__ void __launch_bounds__(512)
pool_mlp_kernel(const u16* __restrict__ hb,
                const int* __restrict__ rs,
                const int* __restrict__ csr,
                const float* __restrict__ fc1_w, const float* __restrict__ fc1_b,
                const float* __restrict__ fc2_w, const float* __restrict__ fc2_b,
                const float* __restrict__ fc3_w, const float* __restrict__ fc3_b,
                float* __restrict__ out, int nsets, int nnodes) {
  __shared__ float s_p[64][FEAT + 4];
  __shared__ int s_idx[8][IDXE + 16];
  const int tid = threadIdx.x;
  const int wv = __builtin_amdgcn_readfirstlane(tid >> 6);
  const int lane = tid & 63;
  const int sub = lane >> 4;
  const int ch = lane & 15;
  const int base = blockIdx.x * 64;

  int wbase = base + wv * 8;
  if (wbase < nsets) {
    gather8(hb, rs, csr, &s_idx[wv][0], wbase, nsets, nnodes, sub, ch, lane,
            [&](int t, float4 acc) {
              if (sub == 0) *(float4*)&s_p[wv * 8 + t][ch * 4] = acc;
            });
  }
  __syncthreads();

  // fc1 (64->64) + ELU, in place; wave covers cols [wv*8, +8)
  {
    const int jb = wv * 8;
    float acc[8];
#pragma unroll
    for (int jj = 0; jj < 8; ++jj) acc[jj] = fc1_b[jb + jj];
    for (int k = 0; k < FEAT; k += 4) {
      const float4 pv = *(const float4*)&s_p[lane][k];
      const float pk[4] = {pv.x, pv.y, pv.z, pv.w};
#pragma unroll
      for (int kk = 0; kk < 4; ++kk) {
        const float* w = fc1_w + (k + kk) * FEAT + jb;
#pragma unroll
        for (int jj = 0; jj < 8; ++jj) acc[jj] += pk[kk] * w[jj];
      }
    }
    __syncthreads();
#pragma unroll
    for (int jj = 0; jj < 8; ++jj) {
      float a = acc[jj];
      s_p[lane][jb + jj] = a > 0.f ? a : (__expf(a) - 1.f);
    }
  }
  __syncthreads();

  // fc2 (64->32) + ELU; wave covers cols [wv*4, +4)
  {
    const int jb = wv * 4;
    float acc[4];
#pragma unroll
    for (int jj = 0; jj < 4; ++jj) acc[jj] = fc2_b[jb + jj];
    for (int k = 0; k < FEAT; k += 4) {
      const float4 tv = *(const float4*)&s_p[lane][k];
      const float tk[4] = {tv.x, tv.y, tv.z, tv.w};
#pragma unroll
      for (int kk = 0; kk < 4; ++kk) {
        const float* w = fc2_w + (k + kk) * 32 + jb;
#pragma unroll
        for (int jj = 0; jj < 4; ++jj) acc[jj] += tk[kk] * w[jj];
      }
    }
    __syncthreads();
#pragma unroll
    for (int jj = 0; jj < 4; ++jj) {
      float a = acc[jj];
      s_p[lane][jb + jj] = a > 0.f ? a : (__expf(a) - 1.f);
    }
  }
  __syncthreads();

  // fc3 (32->2) + log_softmax; wave 0, lane = set
  if (wv == 0) {
    int s = base + lane;
    if (s < nsets) {
      float a0 = fc3_b[0], a1 = fc3_b[1];
      for (int k = 0; k < 32; k += 4) {
        const float4 tv = *(const float4*)&s_p[lane][k];
        const float tk[4] = {tv.x, tv.y, tv.z, tv.w};
#pragma unroll
        for (int kk = 0; kk < 4; ++kk) {
          a0 += tk[kk] * fc3_w[(k + kk) * 2 + 0];
          a1 += tk[kk] * fc3_w[(k + kk) * 2 + 1];
        }
      }
      float m = fmaxf(a0, a1);
      float lse = m + logf(__expf(a0 - m) + __expf(a1 - m));
      float2 r = {a0 - lse, a1 - lse};
      *(float2*)(out + (size_t)s * 2) = r;
    }
  }
}

extern "C" void kernel_launch(void* const* d_in, const int* in_sizes, int n_in,
                              void* d_out, int out_size, void* d_ws, size_t ws_size,
                              hipStream_t stream) {
  const float* x        = (const float*)d_in[0];
  const int* edge_src   = (const int*)d_in[1];
  const int* edge_dst   = (const int*)d_in[2];
  const int* gather_idx = (const int*)d_in[3];
  const int* seg_idx    = (const int*)d_in[4];
  const float* w_root0  = (const float*)d_in[5];
  const float* w_rel0   = (const float*)d_in[6];
  const float* b0       = (const float*)d_in[7];
  const float* w_root_h = (const float*)d_in[8];
  const float* w_rel_h  = (const float*)d_in[9];
  const float* b_h      = (const float*)d_in[10];
  const float* fc1_w    = (const float*)d_in[11];
  const float* fc1_b    = (const float*)d_in[12];
  const float* fc2_w    = (const float*)d_in[13];
  const float* fc2_b    = (const float*)d_in[14];
  const float* fc3_w    = (const float*)d_in[15];
  const float* fc3_b    = (const float*)d_in[16];

  const int N = in_sizes[0] / FEAT;
  const int E = in_sizes[1];
  const int A = in_sizes[3];
  const int S = out_size / 2;

  const int NB_e = (N + BSZ - 1) / BSZ;
  const int NB_p = (S + BSZ - 1) / BSZ;
  const int L_e = NB_e * CH, L_p = NB_p * CH;
  const int nb_e = (L_e + SCHUNK - 1) / SCHUNK;
  const int nb_p = (L_p + SCHUNK - 1) / SCHUNK;
  const int g_e = (L_e + 255) / 256, g_p = (L_p + 255) / 256;

  size_t hrow_bytes = (size_t)(N + 1) * FEAT * sizeof(u16);   // +1 sentinel row
  size_t h8_bytes   = (size_t)(N + 1) * FEAT;                 // fp8 tables
  char* ws = (char*)d_ws;
  size_t off = 0;
  auto alloc = [&](size_t bytes) { void* p = ws + off; off += (bytes + 15) & ~(size_t)15; return p; };
  u16* xb       = (u16*)alloc(hrow_bytes);
  u16* b1b      = (u16*)alloc(hrow_bytes);
  u16* b2b      = (u16*)alloc(hrow_bytes);
  u8* xb8       = (u8*)alloc(h8_bytes);
  u8* h8a       = (u8*)alloc(h8_bytes);
  u8* h8b       = (u8*)alloc(h8_bytes);
  int* csr_e    = (int*)alloc((size_t)(E + 16) * 4);          // +16 slack (batch overread)
  int* bin_e    = (int*)alloc((size_t)E * 4);
  int* rs_e     = (int*)alloc((size_t)(N + 1) * 4);
  int* counts_e = (int*)alloc((size_t)L_e * 4);
  int* bbase_e  = (int*)alloc((size_t)(NB_e + 1) * 4);
  int* csr_p    = (int*)alloc((size_t)(A + 16) * 4);
  int* bin_p    = (int*)alloc((size_t)A * 4);
  int* rs_p     = (int*)alloc((size_t)(S + 1) * 4);
  int* counts_p = (int*)alloc((size_t)L_p * 4);
  int* bbase_p  = (int*)alloc((size_t)(NB_p + 1) * 4);
  int* bsums_e  = (int*)alloc(256 * 4);
  int* bsums_p  = (int*)alloc(256 * 4);
  u16* wpack    = (u16*)alloc((size_t)3 * 16 * 64 * 8 * sizeof(u16));

  dim3 blk(256);
  dim3 blk512(512);

  int n4 = N * FEAT / 4;
  int g_cvt = (n4 + 255) / 256;
  int g_pp = 13;   // 12 prepack blocks + 1 sentinel-zero block

  // ---- build both CSRs (+ cvt + prepack folded into pass 1a) ----
  p1a2f_kernel<<<2 * CH + g_cvt + g_pp, blk, 0, stream>>>(
      edge_dst, counts_e, E, NB_e, seg_idx, counts_p, A, NB_p,
      x, xb, xb8, n4, g_cvt, w_root0, w_rel0, w_root_h, w_rel_h, wpack);
  scan1_kernel<<<nb_e + nb_p, blk, 0, stream>>>(counts_e, bsums_e, L_e, nb_e,
                                                counts_p, bsums_p, L_p);
  scan3_kernel<<<g_e + g_p, blk, 0, stream>>>(counts_e, bsums_e, bbase_e, L_e, NB_e, E, nb_e, g_e,
                                              counts_p, bsums_p, bbase_p, L_p, NB_p, A, nb_p);
  p1b2_kernel<<<2 * CH, blk, 0, stream>>>(edge_src, edge_dst, counts_e, bin_e, E, NB_e,
                                          gather_idx, seg_idx, counts_p, bin_p, A, NB_p);
  p2_kernel<<<NB_e + NB_p, blk, 0, stream>>>(bin_e, bbase_e, csr_e, rs_e, N, NB_e,
                                             bin_p, bbase_p, csr_p, rs_p, S);

  int lgrid = (N + 31) / 32;
  int pgrid = (S + 63) / 64;

  // ---- 3 fused GraphConv layers (fp8 gather tables) ----
  layer_fused_kernel<<<lgrid, blk, 0, stream>>>(xb, xb8, rs_e, csr_e, wpack,
                                                b0, b1b, h8a, N);
  layer_fused_kernel<<<lgrid, blk, 0, stream>>>(b1b, h8a, rs_e, csr_e, wpack + 16 * 64 * 8,
                                                b_h, b2b, h8b, N);
  layer_fused_kernel<<<lgrid, blk, 0, stream>>>(b2b, h8b, rs_e, csr_e, wpack + 2 * 16 * 64 * 8,
                                                b_h + FEAT, b1b, (u8*)nullptr, N);

  // ---- fused pooling + MLP head + log_softmax ----
  pool_mlp_kernel<<<pgrid, blk512, 0, stream>>>(b1b, rs_p, csr_p,
                                                fc1_w, fc1_b, fc2_w, fc2_b, fc3_w, fc3_b,
                                                (float*)d_out, S, N);
}